// Round 2
// baseline (5569.604 us; speedup 1.0000x reference)
//
#include <hip/hip_runtime.h>
#include <stdint.h>

typedef __bf16 bf16_t;
typedef __bf16 bf16x8 __attribute__((ext_vector_type(8)));
typedef float floatx16 __attribute__((ext_vector_type(16)));
typedef unsigned int u32;

#define TOK_S 512
#define NWGS  32

struct KParams {
  const int* tok;
  const float* emb;
  const float* W1[4]; const float* b1[4];
  const float* W2[4]; const float* b2[4];
  const float* Wd; const float* bd; const float* Wout; const float* bout;
  float* out;
  uint16_t* h1; uint16_t* h2;   // internal double-buffered [2][64][256] bf16
  u32* cnt; u32* gen;
  float* dstage;                // [64][128] fp32
};

__device__ __forceinline__ float sigf(float x) { return 1.f / (1.f + __expf(-x)); }
__device__ __forceinline__ float tanhf_fast(float x) { return 1.f - 2.f / (__expf(2.f * x) + 1.f); }

__device__ __forceinline__ u32 pack2(float a, float b) {
  uint16_t x = __builtin_bit_cast(uint16_t, (bf16_t)a);
  uint16_t y = __builtin_bit_cast(uint16_t, (bf16_t)b);
  return ((u32)y << 16) | (u32)x;
}

// Device-scope sense-reversing barrier across 32 co-resident WGs.
__device__ __forceinline__ void gridbar(u32* cnt, u32* gen, u32 target) {
  __syncthreads();
  if (threadIdx.x == 0) {
    __threadfence();  // publish h stores (agent scope)
    u32 old = __hip_atomic_fetch_add(cnt, 1u, __ATOMIC_ACQ_REL, __HIP_MEMORY_SCOPE_AGENT);
    if (old == NWGS - 1u) {
      __hip_atomic_store(cnt, 0u, __ATOMIC_RELAXED, __HIP_MEMORY_SCOPE_AGENT);
      __hip_atomic_store(gen, target, __ATOMIC_RELEASE, __HIP_MEMORY_SCOPE_AGENT);
    } else {
      while (__hip_atomic_load(gen, __ATOMIC_ACQUIRE, __HIP_MEMORY_SCOPE_AGENT) < target) {}
    }
    __threadfence();  // acquire side: refresh this CU's view of peer h-slices
  }
  __syncthreads();
}

// Persistent LSTM layer. 16 WGs per layer, each owns 16 hidden units (64 gate cols).
// Per step, GEMM C[64b][64g] = z @ Wslab is split into two K-phases sharing one
// A-buffer (keeps LDS < 64 KB). B (weights) live in VGPRs as bf16 MFMA fragments,
// loaded once from the fp32 globals and reused 512x. c-state stays in registers.
template<int LAYER>
__device__ void run_layer(const KParams& p, int sub, char* abuf, float* cstage,
                          float* biasl, u32& bar)
{
  constexpr int NSA = (LAYER == 0) ? 20 : 16;   // phase-A K/16 (L0: x 300->pad 320)
  constexpr int NSB = 16;                       // phase-B K/16 (h part, 256)
  constexpr int SA  = (LAYER == 0) ? 656 : 528; // phase-A row stride bytes (+8elt pad)
  constexpr int SB  = 528;                      // phase-B row stride bytes

  const int tid = threadIdx.x;
  const int w = tid >> 6, l = tid & 63, q = l >> 5, lr = l & 31;
  const int mh = w & 1, nh = w >> 1;  // wave tile: rows [32*mh,+32), cols [32*nh,+32)

  if (tid < 64) {
    const float* bv = (LAYER == 0) ? p.b1[tid >> 4] : p.b2[tid >> 4];
    biasl[tid] = bv[sub * 16 + (tid & 15)];
  }

  // ---- one-time: weight slices fp32 -> bf16 MFMA B-fragments in registers ----
  const int c  = nh * 32 + lr;          // col 0..63 within this WG's slab
  const float* Wg = (LAYER == 0) ? p.W1[c >> 4] : p.W2[c >> 4];
  const int un = sub * 16 + (c & 15);
  bf16x8 wfA[NSA], wfB[NSB];
#pragma unroll
  for (int s = 0; s < NSA; ++s)
#pragma unroll
    for (int j = 0; j < 8; ++j) {
      int k = 16 * s + 8 * q + j;
      float v;
      if (LAYER == 0) v = (k < 300) ? Wg[k * 256 + un] : 0.f;  // K-pad rows = 0
      else            v = Wg[k * 256 + un];
      wfA[s][j] = (bf16_t)v;
    }
#pragma unroll
  for (int s = 0; s < NSB; ++s)
#pragma unroll
    for (int j = 0; j < 8; ++j) {
      int k = 16 * s + 8 * q + j;
      int row = (LAYER == 0) ? (300 + k) : (256 + k);
      wfB[s][j] = (bf16_t)Wg[row * 256 + un];
    }

  float cs[4] = {0.f, 0.f, 0.f, 0.f};  // c-state: thread t owns (b,u) for p=t+256k

  for (int r = 0; r < 513; ++r) {
    const bool active = (LAYER == 0) ? (r < 512) : (r >= 1);
    if (active) {
      const int s = (LAYER == 0) ? r : (r - 1);

      // ---- phase A stage ----
      if (LAYER == 0) {
        int b = tid >> 2, qq = tid & 3;
        int tokv = p.tok[b * TOK_S + s];
        const float4* src = (const float4*)(p.emb + (size_t)tokv * 300);
        char* dst = abuf + b * SA;
        for (int j = qq; j < 75; j += 4) {      // 75 float4 = 300 floats
          float4 v = src[j];
          *(u32*)(dst + 8 * j)     = pack2(v.x, v.y);
          *(u32*)(dst + 8 * j + 4) = pack2(v.z, v.w);
        }
        for (int i = tid; i < 640; i += 256) {  // zero K-pad elements 300..319
          int bb = i / 10, cc = i % 10;
          *(u32*)(abuf + bb * SA + 600 + cc * 4) = 0u;
        }
      } else {
        const u32* hp1 = (const u32*)(p.h1 + (s & 1) * 16384);  // h1[s]
        for (int i = tid; i < 8192; i += 256) {
          int bb = i >> 7, cc = i & 127;
          *(u32*)(abuf + bb * SA + cc * 4) = hp1[i];
        }
      }
      __syncthreads();

      // ---- MFMA phase A ----
      floatx16 acc;
#pragma unroll
      for (int e = 0; e < 16; ++e) acc[e] = 0.f;
      {
        const char* arow = abuf + (mh * 32 + lr) * SA + q * 16;
#pragma unroll
        for (int s2 = 0; s2 < NSA; ++s2) {
          bf16x8 af = *(const bf16x8*)(arow + s2 * 32);
          acc = __builtin_amdgcn_mfma_f32_32x32x16_bf16(af, wfA[s2], acc, 0, 0, 0);
        }
      }
      __syncthreads();  // all waves done reading phase-A abuf before overwrite

      // ---- phase B stage (h part) ----
      {
        const u32* hp = (LAYER == 0) ? (const u32*)(p.h1 + ((s + 1) & 1) * 16384)
                                     : (const u32*)(p.h2 + ((s + 1) & 1) * 16384);
        for (int i = tid; i < 8192; i += 256) {
          int bb = i >> 7, cc = i & 127;
          *(u32*)(abuf + bb * SB + cc * 4) = hp[i];
        }
      }
      __syncthreads();

      // ---- MFMA phase B ----
      {
        const char* arow = abuf + (mh * 32 + lr) * SB + q * 16;
#pragma unroll
        for (int s2 = 0; s2 < NSB; ++s2) {
          bf16x8 af = *(const bf16x8*)(arow + s2 * 32);
          acc = __builtin_amdgcn_mfma_f32_32x32x16_bf16(af, wfB[s2], acc, 0, 0, 0);
        }
      }
      // stage C (C/D map: col=lane&31, row=(e&3)+8*(e>>2)+4*(lane>>5))
#pragma unroll
      for (int e = 0; e < 16; ++e) {
        int ri = (e & 3) + 8 * (e >> 2) + 4 * q;
        cstage[(mh * 32 + ri) * 68 + nh * 32 + lr] = acc[e];
      }
      __syncthreads();

      // ---- LSTM cell elementwise + bf16 h store ----
      bf16_t* hout = (bf16_t*)((LAYER == 0 ? p.h1 : p.h2) + (s & 1) * 16384);
#pragma unroll
      for (int kk = 0; kk < 4; ++kk) {
        int pp = tid + 256 * kk, b = pp >> 4, u = pp & 15;
        float fv = cstage[b * 68 +      u] + biasl[u];
        float iv = cstage[b * 68 + 16 + u] + biasl[16 + u];
        float gv = cstage[b * 68 + 32 + u] + biasl[32 + u];
        float ov = cstage[b * 68 + 48 + u] + biasl[48 + u];
        float cn = sigf(fv) * cs[kk] + sigf(iv) * tanhf_fast(gv);
        cs[kk] = cn;
        hout[b * 256 + sub * 16 + u] = (bf16_t)(sigf(ov) * tanhf_fast(cn));
      }
    }
    ++bar;
    gridbar(p.cnt, p.gen, bar);
  }
}

__global__ __launch_bounds__(256, 1) void lstm_main(KParams p)
{
  __shared__ __align__(16) char  abuf[64 * 656];   // 41984 B (phase-A max)
  __shared__ float cstage[64 * 68];                // 17408 B
  __shared__ float biasl[64];                      // total LDS ~59.7 KB < 64 KB
  const int wg = blockIdx.x;
  const int sub = wg & 15;
  u32 bar = 0;
  if (wg < 16) run_layer<0>(p, sub, abuf, cstage, biasl, bar);
  else         run_layer<1>(p, sub, abuf, cstage, biasl, bar);

  // ---- dense head: d = relu(h2_last @ Wd + bd); out = sigmoid(d @ Wout + bout) ----
  const int tid = threadIdx.x;
  if (wg < 16) {  // 16 WGs x 8 cols of DNS=128
    const bf16_t* h2f = (const bf16_t*)(p.h2 + 16384);   // h2[511] is in buf[1]
    for (int idx = tid; idx < 512; idx += 256) {
      int b = idx >> 3, cc = wg * 8 + (idx & 7);
      float a = p.bd[cc];
#pragma unroll 8
      for (int k = 0; k < 256; ++k) a += (float)h2f[b * 256 + k] * p.Wd[k * 128 + cc];
      p.dstage[b * 128 + cc] = fmaxf(a, 0.f);
    }
  }
  ++bar;
  gridbar(p.cnt, p.gen, bar);
  if (wg == 16 && tid < 64) {
    float a = p.bout[0];
#pragma unroll 8
    for (int cc = 0; cc < 128; ++cc) a += p.dstage[tid * 128 + cc] * p.Wout[cc];
    p.out[tid] = sigf(a);
  }
}

// Zero h buffers (h[-1]=0) + barrier state; ws is re-poisoned 0xAA before every launch.
__global__ void init_ws(u32* ws32) {
  int i = blockIdx.x * 256 + threadIdx.x;
  if (i < 32832) ws32[i] = 0u;   // 131072 B h-bufs + 256 B barrier state
}

extern "C" void kernel_launch(void* const* d_in, const int* in_sizes, int n_in,
                              void* d_out, int out_size, void* d_ws, size_t ws_size,
                              hipStream_t stream)
{
  KParams p;
  p.tok = (const int*)d_in[0];
  p.emb = (const float*)d_in[1];
  for (int g = 0; g < 4; ++g) {
    p.W1[g] = (const float*)d_in[2 + 2 * g];
    p.b1[g] = (const float*)d_in[3 + 2 * g];
    p.W2[g] = (const float*)d_in[10 + 2 * g];
    p.b2[g] = (const float*)d_in[11 + 2 * g];
  }
  p.Wd   = (const float*)d_in[18];
  p.bd   = (const float*)d_in[19];
  p.Wout = (const float*)d_in[20];
  p.bout = (const float*)d_in[21];
  p.out  = (float*)d_out;
  char* ws = (char*)d_ws;
  p.h1     = (uint16_t*)ws;              // 2 x 32768 B
  p.h2     = (uint16_t*)(ws + 65536);    // 2 x 32768 B
  p.cnt    = (u32*)(ws + 131072);
  p.gen    = (u32*)(ws + 131200);
  p.dstage = (float*)(ws + 131328);      // 32768 B fp32

  hipLaunchKernelGGL(init_ws, dim3(129), dim3(256), 0, stream, (u32*)d_ws);
  hipLaunchKernelGGL(lstm_main, dim3(NWGS), dim3(256), 0, stream, p);
}

// Round 3
// 2768.081 us; speedup vs baseline: 2.0121x; 2.0121x over previous
//
#include <hip/hip_runtime.h>
#include <stdint.h>

typedef __bf16 bf16_t;
typedef __bf16 bf16x8 __attribute__((ext_vector_type(8)));
typedef float floatx16 __attribute__((ext_vector_type(16)));
typedef unsigned int u32;
typedef unsigned long long u64;

#define NBAR  32   // recurrent WGs participating in the barrier
#define NPROD 64   // Gx producer WGs

struct KParams {
  const int* tok;
  const float* emb;
  const float* W1[4]; const float* b1[4];
  const float* W2[4]; const float* b2[4];
  const float* Wd; const float* bd; const float* Wout; const float* bout;
  float* out;
  uint16_t* h1; uint16_t* h2;     // double-buffered [2][64][256] bf16
  u32* cnt; u32* gen; u32* rprog; u32* flags;
  float* dstage;                  // [64][128] fp32
  bf16_t* w1bf;                   // [20][1024][16] fragment-ordered x-weights (bf16)
  float* gx;                      // ring: R slabs of [64][1024] fp32
  int R;
};

__device__ __forceinline__ float sigf(float x) { return 1.f / (1.f + __expf(-x)); }
__device__ __forceinline__ float tanhf_fast(float x) { return 1.f - 2.f / (__expf(2.f * x) + 1.f); }

__device__ __forceinline__ u32 pack2(float a, float b) {
  uint16_t x = __builtin_bit_cast(uint16_t, (bf16_t)a);
  uint16_t y = __builtin_bit_cast(uint16_t, (bf16_t)b);
  return ((u32)y << 16) | (u32)x;
}
__device__ __forceinline__ float2 u2f2(u64 v) { union { u64 u; float2 f; } x; x.u = v; return x.f; }

// relaxed agent-scope ops: sc0+sc1 -> bypass L1/L2, coherent at LLC, no cache inv needed
__device__ __forceinline__ u32  ald32(const u32* p) { return __hip_atomic_load(p, __ATOMIC_RELAXED, __HIP_MEMORY_SCOPE_AGENT); }
__device__ __forceinline__ void ast32(u32* p, u32 v) { __hip_atomic_store(p, v, __ATOMIC_RELAXED, __HIP_MEMORY_SCOPE_AGENT); }
__device__ __forceinline__ u64  ald64(const u64* p) { return __hip_atomic_load(p, __ATOMIC_RELAXED, __HIP_MEMORY_SCOPE_AGENT); }
__device__ __forceinline__ uint16_t ald16(const uint16_t* p) { return __hip_atomic_load(p, __ATOMIC_RELAXED, __HIP_MEMORY_SCOPE_AGENT); }

// Monotonic-count barrier across NBAR WGs. Release side: one __threadfence (L2 is
// clean -> cheap wb). Acquire side: relaxed spin + compiler fence only — all
// post-barrier cross-WG reads are scoped (LLC), so no cache invalidate is needed.
__device__ __forceinline__ void gridbar(u32* cnt, u32* gen, u32 target) {
  __syncthreads();
  if (threadIdx.x == 0) {
    __threadfence();
    u32 old = __hip_atomic_fetch_add(cnt, 1u, __ATOMIC_RELAXED, __HIP_MEMORY_SCOPE_AGENT);
    if (old == target * NBAR - 1u) {
      ast32(gen, target);
    } else {
      while (ald32(gen) < target) {}
    }
    __atomic_signal_fence(__ATOMIC_ACQUIRE);
  }
  __syncthreads();
}

// Stage one 64x256 bf16 h-matrix (scoped, from LLC) into LDS rows of stride 576 B.
__device__ __forceinline__ void stage_h(const u64* hp, char* smem) {
  const int tid = threadIdx.x;
  u64 tmp[16];
#pragma unroll
  for (int t = 0; t < 16; ++t) tmp[t] = ald64(hp + tid + 256 * t);  // 16 outstanding
#pragma unroll
  for (int t = 0; t < 16; ++t) {
    int i = tid + 256 * t, b = i >> 6, cc = i & 63;
    *(u64*)(smem + b * 576 + cc * 8) = tmp[t];
  }
}

// ---------------- Layer 0 (recurrent part only; x handled by producers) --------
__device__ void run_l0(const KParams& p, int sub, char* smem, float* biasl, u32& bar)
{
  const int tid = threadIdx.x;
  const int w = tid >> 6, l = tid & 63, q = l >> 5, lr = l & 31;
  const int mh = w & 1, nh = w >> 1;

  if (tid < 64) biasl[tid] = p.b1[tid >> 4][sub * 16 + (tid & 15)];

  // W1 h-part rows 300..555 -> register B-fragments (reused 512x)
  const int c = nh * 32 + lr;
  const float* Wg = p.W1[c >> 4];
  const int un = sub * 16 + (c & 15);
  bf16x8 wf[16];
#pragma unroll
  for (int s = 0; s < 16; ++s)
#pragma unroll
    for (int j = 0; j < 8; ++j) {
      int k = 16 * s + 8 * q + j;
      wf[s][j] = (bf16_t)Wg[(300 + k) * 256 + un];
    }

  float cs[2][2] = {{0.f, 0.f}, {0.f, 0.f}};
  float* cst = (float*)smem;    // cstage aliases smem (disjoint in time)

  for (int r = 0; r < 513; ++r) {
    if (r < 512) {
      const int s = r;
      if (tid == 0) {
        while (ald32(&p.flags[s]) == 0) {}
        __atomic_signal_fence(__ATOMIC_ACQUIRE);
      }
      stage_h((const u64*)(p.h1 + ((s + 1) & 1) * 16384), smem);
      __syncthreads();

      floatx16 acc;
#pragma unroll
      for (int e = 0; e < 16; ++e) acc[e] = 0.f;
      const char* arow = smem + (mh * 32 + lr) * 576 + q * 16;
#pragma unroll
      for (int s2 = 0; s2 < 16; ++s2) {
        bf16x8 af = *(const bf16x8*)(arow + 32 * s2);
        acc = __builtin_amdgcn_mfma_f32_32x32x16_bf16(af, wf[s2], acc, 0, 0, 0);
      }
      __syncthreads();
#pragma unroll
      for (int e = 0; e < 16; ++e) {
        int ri = (e & 3) + 8 * (e >> 2) + 4 * q;
        cst[(mh * 32 + ri) * 68 + nh * 32 + lr] = acc[e];
      }
      __syncthreads();

      const float* slab = p.gx + (size_t)(s % p.R) * 65536u;
      uint16_t* hout = p.h1 + (s & 1) * 16384;
#pragma unroll
      for (int kk = 0; kk < 2; ++kk) {
        int pp = tid + 256 * kk, b = pp >> 3, u = (pp & 7) * 2;
        float2 pf = *(float2*)&cst[b * 68 +      u];
        float2 pi = *(float2*)&cst[b * 68 + 16 + u];
        float2 pg = *(float2*)&cst[b * 68 + 32 + u];
        float2 po = *(float2*)&cst[b * 68 + 48 + u];
        const float* gb = slab + b * 1024 + sub * 64 + u;
        float2 gf = u2f2(ald64((const u64*)(gb)));
        float2 gi = u2f2(ald64((const u64*)(gb + 16)));
        float2 gg = u2f2(ald64((const u64*)(gb + 32)));
        float2 go = u2f2(ald64((const u64*)(gb + 48)));
        float hv[2];
#pragma unroll
        for (int j = 0; j < 2; ++j) {
          float fj = sigf((j ? pf.y : pf.x) + (j ? gf.y : gf.x) + biasl[u + j]);
          float ij = sigf((j ? pi.y : pi.x) + (j ? gi.y : gi.x) + biasl[16 + u + j]);
          float gj = tanhf_fast((j ? pg.y : pg.x) + (j ? gg.y : gg.x) + biasl[32 + u + j]);
          float oj = sigf((j ? po.y : po.x) + (j ? go.y : go.x) + biasl[48 + u + j]);
          float cn = fj * cs[kk][j] + ij * gj;
          cs[kk][j] = cn;
          hv[j] = oj * tanhf_fast(cn);
        }
        ast32((u32*)(hout + b * 256 + sub * 16 + u), pack2(hv[0], hv[1]));
      }
    }
    ++bar;
    gridbar(p.cnt, p.gen, bar);
    if (sub == 0 && tid == 0) ast32(p.rprog, (u32)(r + 1));  // consumer progress for ring
  }
}

// ---------------- Layer 1 (z = [h1_t | h2_{t-1}], K=512 in two phases) ---------
__device__ void run_l1(const KParams& p, int sub, char* smem, float* biasl, u32& bar)
{
  const int tid = threadIdx.x;
  const int w = tid >> 6, l = tid & 63, q = l >> 5, lr = l & 31;
  const int mh = w & 1, nh = w >> 1;

  if (tid < 64) biasl[tid] = p.b2[tid >> 4][sub * 16 + (tid & 15)];

  const int c = nh * 32 + lr;
  const float* Wg = p.W2[c >> 4];
  const int un = sub * 16 + (c & 15);
  bf16x8 wfA[16], wfB[16];
#pragma unroll
  for (int s = 0; s < 16; ++s)
#pragma unroll
    for (int j = 0; j < 8; ++j) {
      int k = 16 * s + 8 * q + j;
      wfA[s][j] = (bf16_t)Wg[k * 256 + un];
      wfB[s][j] = (bf16_t)Wg[(256 + k) * 256 + un];
    }

  float cs[2][2] = {{0.f, 0.f}, {0.f, 0.f}};
  float* cst = (float*)smem;

  for (int r = 0; r < 513; ++r) {
    if (r >= 1) {
      const int s = r - 1;
      // phase A: h1[s]
      stage_h((const u64*)(p.h1 + (s & 1) * 16384), smem);
      __syncthreads();
      floatx16 acc;
#pragma unroll
      for (int e = 0; e < 16; ++e) acc[e] = 0.f;
      const char* arow = smem + (mh * 32 + lr) * 576 + q * 16;
#pragma unroll
      for (int s2 = 0; s2 < 16; ++s2) {
        bf16x8 af = *(const bf16x8*)(arow + 32 * s2);
        acc = __builtin_amdgcn_mfma_f32_32x32x16_bf16(af, wfA[s2], acc, 0, 0, 0);
      }
      __syncthreads();
      // phase B: h2[s-1]
      stage_h((const u64*)(p.h2 + ((s + 1) & 1) * 16384), smem);
      __syncthreads();
#pragma unroll
      for (int s2 = 0; s2 < 16; ++s2) {
        bf16x8 af = *(const bf16x8*)(arow + 32 * s2);
        acc = __builtin_amdgcn_mfma_f32_32x32x16_bf16(af, wfB[s2], acc, 0, 0, 0);
      }
      __syncthreads();
#pragma unroll
      for (int e = 0; e < 16; ++e) {
        int ri = (e & 3) + 8 * (e >> 2) + 4 * q;
        cst[(mh * 32 + ri) * 68 + nh * 32 + lr] = acc[e];
      }
      __syncthreads();

      uint16_t* hout = p.h2 + (s & 1) * 16384;
#pragma unroll
      for (int kk = 0; kk < 2; ++kk) {
        int pp = tid + 256 * kk, b = pp >> 3, u = (pp & 7) * 2;
        float2 pf = *(float2*)&cst[b * 68 +      u];
        float2 pi = *(float2*)&cst[b * 68 + 16 + u];
        float2 pg = *(float2*)&cst[b * 68 + 32 + u];
        float2 po = *(float2*)&cst[b * 68 + 48 + u];
        float hv[2];
#pragma unroll
        for (int j = 0; j < 2; ++j) {
          float fj = sigf((j ? pf.y : pf.x) + biasl[u + j]);
          float ij = sigf((j ? pi.y : pi.x) + biasl[16 + u + j]);
          float gj = tanhf_fast((j ? pg.y : pg.x) + biasl[32 + u + j]);
          float oj = sigf((j ? po.y : po.x) + biasl[48 + u + j]);
          float cn = fj * cs[kk][j] + ij * gj;
          cs[kk][j] = cn;
          hv[j] = oj * tanhf_fast(cn);
        }
        ast32((u32*)(hout + b * 256 + sub * 16 + u), pack2(hv[0], hv[1]));
      }
    }
    ++bar;
    gridbar(p.cnt, p.gen, bar);
  }
}

// ---------------- Gx producers: Gx[s] = x_s @ W1x, K=300 (pad 320) -------------
__device__ void run_prod(const KParams& p, int pw, char* smem)
{
  const int tid = threadIdx.x;
  const int w = tid >> 6, l = tid & 63, q = l >> 5, lr = l & 31;
  const int mh = w & 1, chalf = w >> 1;
  const int R = p.R;

  for (int jj = 0; jj < 512 / NPROD; ++jj) {
    const int s = pw + NPROD * jj;
    if (tid == 0 && s >= R) {                     // ring throttle
      u32 need = (u32)(s - R + 1);
      while (ald32(p.rprog) < need) {}
    }
    __syncthreads();
    // stage A: emb gather -> bf16 LDS, row stride 656 B, zero pad band 300..319
    {
      int b = tid >> 2, qq = tid & 3;
      int tokv = p.tok[b * 512 + s];
      const float4* src = (const float4*)(p.emb + (size_t)tokv * 300);
      char* dst = smem + b * 656;
      for (int j2 = qq; j2 < 75; j2 += 4) {
        float4 v = src[j2];
        *(u32*)(dst + 8 * j2)     = pack2(v.x, v.y);
        *(u32*)(dst + 8 * j2 + 4) = pack2(v.z, v.w);
      }
      for (int i = tid; i < 640; i += 256) {
        int bb = i / 10, cc2 = i % 10;
        *(u32*)(smem + bb * 656 + 600 + cc2 * 4) = 0u;
      }
    }
    __syncthreads();

    bf16x8 afr[20];
    const char* arow = smem + (mh * 32 + lr) * 656 + q * 16;
#pragma unroll
    for (int kt = 0; kt < 20; ++kt) afr[kt] = *(const bf16x8*)(arow + 32 * kt);

    float* slab = p.gx + (size_t)(s % R) * 65536u;
    for (int c2 = 0; c2 < 16; ++c2) {
      int ct = chalf * 16 + c2;
      int n = ct * 32 + lr;
      floatx16 acc;
#pragma unroll
      for (int e = 0; e < 16; ++e) acc[e] = 0.f;
#pragma unroll
      for (int kt = 0; kt < 20; ++kt) {
        bf16x8 bf = ((const bf16x8*)p.w1bf)[(kt * 1024 + n) * 2 + q];
        acc = __builtin_amdgcn_mfma_f32_32x32x16_bf16(afr[kt], bf, acc, 0, 0, 0);
      }
#pragma unroll
      for (int e = 0; e < 16; ++e) {
        int ri = (e & 3) + 8 * (e >> 2) + 4 * q;
        ast32((u32*)(slab + (mh * 32 + ri) * 1024 + n), __builtin_bit_cast(u32, acc[e]));
      }
    }
    __syncthreads();
    if (tid == 0) { __threadfence(); ast32(&p.flags[s], 1u); }
  }
}

__global__ __launch_bounds__(256, 1) void lstm_main(KParams p)
{
  __shared__ __align__(16) char smem[64 * 656];   // 41984 B; cstage aliases base
  __shared__ float biasl[64];
  const int wg = blockIdx.x;
  const int tid = threadIdx.x;
  u32 bar = 0;
  if (wg < 16)       run_l0(p, wg, smem, biasl, bar);
  else if (wg < 32)  run_l1(p, wg - 16, smem, biasl, bar);
  else             { run_prod(p, wg - 32, smem); return; }

  // ---- dense head ----
  if (wg < 16) {
    // stage h2[511] (buf 1) into LDS, then 16 WGs x 8 cols of DNS=128
    stageload: {
      const u64* hp = (const u64*)(p.h2 + 16384);
      u64 tmp[16];
#pragma unroll
      for (int t = 0; t < 16; ++t) tmp[t] = ald64(hp + tid + 256 * t);
#pragma unroll
      for (int t = 0; t < 16; ++t) *(u64*)(smem + (tid + 256 * t) * 8) = tmp[t];
    }
    __syncthreads();
    const bf16_t* h2l = (const bf16_t*)smem;
    for (int idx = tid; idx < 512; idx += 256) {
      int b = idx >> 3, cc = wg * 8 + (idx & 7);
      float a = p.bd[cc];
#pragma unroll 8
      for (int k = 0; k < 256; ++k) a += (float)h2l[b * 256 + k] * p.Wd[k * 128 + cc];
      ast32((u32*)&p.dstage[b * 128 + cc], __builtin_bit_cast(u32, fmaxf(a, 0.f)));
    }
  }
  ++bar;
  gridbar(p.cnt, p.gen, bar);
  if (wg == 16 && tid < 64) {
    float a = p.bout[0];
#pragma unroll 8
    for (int cc = 0; cc < 128; ++cc) {
      u32 dv = ald32((u32*)&p.dstage[tid * 128 + cc]);
      a += __builtin_bit_cast(float, dv) * p.Wout[cc];
    }
    p.out[tid] = sigf(a);
  }
}

// One-time: W1 x-part (rows 0..299, zero-pad to 320) -> bf16 fragment-order
// layout [kt][n][16], n = sub*64 + gate*16 + u matching the consumer's Gx cols.
__global__ void prep_w(KParams p) {
  int idx = blockIdx.x * 256 + threadIdx.x;
  if (idx >= 20 * 1024 * 16) return;
  int kk = idx & 15, n = (idx >> 4) & 1023, kt = idx >> 14;
  int k = kt * 16 + kk;
  int g = (n >> 4) & 3, su = n >> 6, u = n & 15;
  float v = (k < 300) ? p.W1[g][k * 256 + su * 16 + u] : 0.f;
  p.w1bf[idx] = (bf16_t)v;
}

// Zero h buffers + barrier/flag state (ws is re-poisoned 0xAA before every launch)
__global__ void init_ws(u32* ws32) {
  int i = blockIdx.x * 256 + threadIdx.x;
  if (i < 33376) ws32[i] = 0u;   // [0, 133504): h1, h2, cnt, gen, rprog, flags
}

extern "C" void kernel_launch(void* const* d_in, const int* in_sizes, int n_in,
                              void* d_out, int out_size, void* d_ws, size_t ws_size,
                              hipStream_t stream)
{
  KParams p;
  p.tok = (const int*)d_in[0];
  p.emb = (const float*)d_in[1];
  for (int g = 0; g < 4; ++g) {
    p.W1[g] = (const float*)d_in[2 + 2 * g];
    p.b1[g] = (const float*)d_in[3 + 2 * g];
    p.W2[g] = (const float*)d_in[10 + 2 * g];
    p.b2[g] = (const float*)d_in[11 + 2 * g];
  }
  p.Wd   = (const float*)d_in[18];
  p.bd   = (const float*)d_in[19];
  p.Wout = (const float*)d_in[20];
  p.bout = (const float*)d_in[21];
  p.out  = (float*)d_out;

  char* ws = (char*)d_ws;
  p.h1     = (uint16_t*)ws;               // 2 x 32768 B
  p.h2     = (uint16_t*)(ws + 65536);     // 2 x 32768 B
  p.cnt    = (u32*)(ws + 131072);
  p.gen    = (u32*)(ws + 131200);
  p.rprog  = (u32*)(ws + 131328);
  p.flags  = (u32*)(ws + 131456);         // 512 x 4 B -> ends 133504
  p.dstage = (float*)(ws + 133632);       // 32768 B  -> ends 166400
  p.w1bf   = (bf16_t*)(ws + 166400);      // 655360 B -> ends 821760
  p.gx     = (float*)(ws + 821760);       // ring: R x 262144 B

  long avail = (long)ws_size - 821760L;
  int R = (int)(avail / 262144L);
  if (R > 64) R = 64;
  if (R < 1)  R = 1;
  p.R = R;

  hipLaunchKernelGGL(init_ws, dim3(131), dim3(256), 0, stream, (u32*)d_ws);
  hipLaunchKernelGGL(prep_w, dim3(1280), dim3(256), 0, stream, p);
  hipLaunchKernelGGL(lstm_main, dim3(NBAR + NPROD), dim3(256), 0, stream, p);
}